// Round 1
// baseline (952.163 us; speedup 1.0000x reference)
//
#include <hip/hip_runtime.h>
#include <math.h>

#define DEV __device__ __forceinline__

constexpr int B = 2, N = 2048, KK = 8, NF = 64;
constexpr int NODES = B * N;           // 4096
constexpr int GRID_N = NODES / 4;      // 1024 blocks, 4 waves (nodes) per block

// ---- bool input format detection (harness marshalling of jnp bool is unspecified)
DEV int bool_mode(const void* p) {
  unsigned v = *(const unsigned*)p;
  if (v == 0x3f800000u) return 2;      // float32 1.0
  if (v <= 1u) return 1;               // int32 0/1
  return 0;                            // uint8 (0x01010101 for all-true)
}
DEV bool read_mask(const void* p, int i, int mode) {
  if (mode == 2) return ((const float*)p)[i] != 0.f;
  if (mode == 1) return ((const int*)p)[i] != 0;
  return ((const unsigned char*)p)[i] != 0;
}

// sum_k shfl(x,k) * W[k*64+f]  -- 4 accumulators to break the FMA chain
DEV float dot64(float x, const float* W, int f) {
  float a0 = 0.f, a1 = 0.f, a2 = 0.f, a3 = 0.f;
  #pragma unroll
  for (int k = 0; k < 64; k += 4) {
    a0 = fmaf(__shfl(x, k + 0), W[(k + 0) * 64 + f], a0);
    a1 = fmaf(__shfl(x, k + 1), W[(k + 1) * 64 + f], a1);
    a2 = fmaf(__shfl(x, k + 2), W[(k + 2) * 64 + f], a2);
    a3 = fmaf(__shfl(x, k + 3), W[(k + 3) * 64 + f], a3);
  }
  return (a0 + a1) + (a2 + a3);
}

// ---------------- 8-NN edge construction (exact top_k semantics) ----------------
__global__ __launch_bounds__(256) void k_edges(
    const float* __restrict__ states, const void* maskp, const void* toolp,
    int* __restrict__ eidx, int* __restrict__ evalid) {
  __shared__ float px[N], py[N], pz[N];
  __shared__ float addNT[N], addT[N];
  __shared__ unsigned char mArr[N];
  const int b = blockIdx.x >> 3;
  const int i = ((blockIdx.x & 7) << 8) + threadIdx.x;
  const int mm = bool_mode(maskp), mt = bool_mode(toolp);
  for (int j = threadIdx.x; j < N; j += 256) {
    const float* s = states + (size_t)(b * N + j) * 3;
    px[j] = s[0]; py[j] = s[1]; pz[j] = s[2];
    bool mj = read_mask(maskp, b * N + j, mm);
    bool tj = read_mask(toolp, b * N + j, mt);
    mArr[j] = mj ? 1 : 0;
    addNT[j] = mj ? 0.f : 1e10f;                 // receiver non-tool: pair ok iff mask_j
    addT[j]  = (mj && !tj) ? 0.f : 1e10f;        // receiver tool: also cut tool-tool
  }
  __syncthreads();
  const bool mi = read_mask(maskp, b * N + i, mm);
  const bool ti = read_mask(toolp, b * N + i, mt);
  const int base = (b * N + i) * KK;
  float td[KK]; int tj[KK];
  #pragma unroll
  for (int k = 0; k < KK; ++k) { td[k] = 3.0e38f; tj[k] = k; }
  if (mi) {
    const float sx = px[i], sy = py[i], sz = pz[i];
    const float* addp = ti ? addT : addNT;
    #pragma unroll 4
    for (int j = 0; j < N; ++j) {
      float dx = sx - px[j], dy = sy - py[j], dz = sz - pz[j];
      // no-contract so the adjacency bit matches the reference's f32 math
      float dis = __fadd_rn(__fadd_rn(__fmul_rn(dx, dx), __fmul_rn(dy, dy)),
                            __fmul_rn(dz, dz));
      float dd = __fadd_rn(dis, addp[j]);        // masked pairs -> exactly 1e10
      if (dd < td[KK - 1]) {                      // strict < == top_k tie stability
        float cd = dd; int cj = j;
        #pragma unroll
        for (int m = 0; m < KK; ++m) {
          bool sw = cd < td[m];
          float od = td[m]; int oj = tj[m];
          if (sw) { td[m] = cd; tj[m] = cj; cd = od; cj = oj; }
        }
      }
    }
  }
  const float T2 = (float)(0.12 * 0.12);
  #pragma unroll
  for (int k = 0; k < KK; ++k) {
    int jj = tj[k];
    evalid[base + k] = (td[k] < T2 && !(ti && mArr[jj])) ? 1 : 0;
    eidx[base + k] = jj;
  }
}

// ---------------- particle + relation encoders, step-invariant precomputes ------
__global__ __launch_bounds__(256) void k_encode(
    const float* __restrict__ states, const float* __restrict__ a_cur,
    const float* __restrict__ s_delta,
    const float* __restrict__ pe_w1, const float* __restrict__ pe_b1,
    const float* __restrict__ pe_w2, const float* __restrict__ pe_b2,
    const float* __restrict__ re_w1, const float* __restrict__ re_b1,
    const float* __restrict__ re_w2, const float* __restrict__ re_b2,
    const float* __restrict__ re_w3, const float* __restrict__ re_b3,
    const float* __restrict__ rp_w, const float* __restrict__ rp_b,
    const float* __restrict__ pp_w, const float* __restrict__ pp_b,
    const int* __restrict__ eidx, const int* __restrict__ evalid,
    float* __restrict__ p_const, float* __restrict__ rel_const,
    float* __restrict__ eff0) {
  __shared__ float s_re2[64 * 64], s_re3[64 * 64], s_rp0[64 * 64];
  for (int t = threadIdx.x; t < 64 * 64; t += 256) {
    s_re2[t] = re_w2[t]; s_re3[t] = re_w3[t]; s_rp0[t] = rp_w[t];
  }
  __syncthreads();
  const int node = blockIdx.x * 4 + (threadIdx.x >> 6);
  const int f = threadIdx.x & 63;
  const int b = node >> 11, i = node & (N - 1);
  // particle encoder: p_in = [s_delta hist(9) | a_cur x3] @ pe_w1 -> relu -> pe_w2 -> relu
  float a = a_cur[b * N + i];
  float acc = pe_b1[f];
  #pragma unroll
  for (int k = 0; k < 9; ++k) acc = fmaf(s_delta[(b * 9 + k) * N + i], pe_w1[k * 64 + f], acc);
  #pragma unroll
  for (int k = 9; k < 12; ++k) acc = fmaf(a, pe_w1[k * 64 + f], acc);
  float h = fmaxf(acc, 0.f);
  float pe = fmaxf(pe_b2[f] + dot64(h, pe_w2, f), 0.f);
  eff0[node * 64 + f] = pe;
  // p_const = pp_b + p_enc @ pp_w[0:64]   (step-invariant part of node update)
  p_const[node * 64 + f] = pp_b[f] + dot64(pe, pp_w, f);
  // relation encoder per valid edge; fold into rel_const = rp_b + rel_enc @ rp_w[0:64]
  const float sx = states[(b * N + i) * 3], sy = states[(b * N + i) * 3 + 1],
              sz = states[(b * N + i) * 3 + 2];
  for (int e = 0; e < KK; ++e) {
    if (!evalid[node * KK + e]) continue;
    int j = eidx[node * KK + e];
    float as = a_cur[b * N + j];
    float dx = sx - states[(b * N + j) * 3];
    float dy = sy - states[(b * N + j) * 3 + 1];
    float dz = sz - states[(b * N + j) * 3 + 2];
    float r = re_b1[f];
    r = fmaf(a,  re_w1[f],       r);
    r = fmaf(as, re_w1[64 + f],  r);
    r = fmaf(dx, re_w1[128 + f], r);
    r = fmaf(dy, re_w1[192 + f], r);
    r = fmaf(dz, re_w1[256 + f], r);
    float h1 = fmaxf(r, 0.f);
    float h2 = fmaxf(re_b2[f] + dot64(h1, s_re2, f), 0.f);
    float h3 = fmaxf(re_b3[f] + dot64(h2, s_re3, f), 0.f);
    rel_const[(node * KK + e) * 64 + f] = rp_b[f] + dot64(h3, s_rp0, f);
  }
}

// ---------------- one propagation step (ping-pong effect buffers) ---------------
__global__ __launch_bounds__(256) void k_prop(
    const float* __restrict__ rp_w, const float* __restrict__ pp_w,
    const int* __restrict__ eidx, const int* __restrict__ evalid,
    const float* __restrict__ p_const, const float* __restrict__ rel_const,
    const float* __restrict__ effIn, float* __restrict__ effOut) {
  __shared__ float s_rp1[64 * 64], s_rp2[64 * 64], s_pp1[64 * 64];
  for (int t = threadIdx.x; t < 64 * 64; t += 256) {
    s_rp1[t] = rp_w[64 * 64 + t];        // rows 64..127  (eff_r)
    s_rp2[t] = rp_w[2 * 64 * 64 + t];    // rows 128..191 (eff_s)
    s_pp1[t] = pp_w[64 * 64 + t];        // rows 64..127  (agg)
  }
  __syncthreads();
  const int node = blockIdx.x * 4 + (threadIdx.x >> 6);
  const int f = threadIdx.x & 63;
  const int nb = node & ~(N - 1);
  float effR = effIn[node * 64 + f];
  float agg = 0.f;
  for (int e = 0; e < KK; ++e) {
    if (!evalid[node * KK + e]) continue;
    int j = eidx[node * KK + e];
    float effS = effIn[(nb + j) * 64 + f];
    float acc = rel_const[(node * KK + e) * 64 + f];
    acc += dot64(effR, s_rp1, f);
    acc += dot64(effS, s_rp2, f);
    agg += fmaxf(acc, 0.f);
  }
  float o = p_const[node * 64 + f] + dot64(agg, s_pp1, f);
  effOut[node * 64 + f] = fmaxf(o + effR, 0.f);
}

// ---------------- predictor head + residual add --------------------------------
__global__ __launch_bounds__(256) void k_out(
    const float* __restrict__ states,
    const float* __restrict__ pr_w1, const float* __restrict__ pr_b1,
    const float* __restrict__ pr_w2, const float* __restrict__ pr_b2,
    const float* __restrict__ eff, float* __restrict__ out) {
  const int node = blockIdx.x * 4 + (threadIdx.x >> 6);
  const int f = threadIdx.x & 63;
  float e = eff[node * 64 + f];
  float h = fmaxf(pr_b1[f] + dot64(e, pr_w1, f), 0.f);
  #pragma unroll
  for (int d = 0; d < 3; ++d) {
    float v = h * pr_w2[f * 3 + d];
    #pragma unroll
    for (int o = 32; o > 0; o >>= 1) v += __shfl_xor(v, o);
    if (f == 0) out[node * 3 + d] = states[node * 3 + d] + v + pr_b2[d];
  }
}

extern "C" void kernel_launch(void* const* d_in, const int* in_sizes, int n_in,
                              void* d_out, int out_size, void* d_ws, size_t ws_size,
                              hipStream_t stream) {
  const float* states  = (const float*)d_in[0];
  const float* a_cur   = (const float*)d_in[1];
  const float* s_delta = (const float*)d_in[2];
  const void*  maskp   = d_in[3];
  const void*  toolp   = d_in[4];
  const float* pe_w1 = (const float*)d_in[6];
  const float* pe_b1 = (const float*)d_in[7];
  const float* pe_w2 = (const float*)d_in[8];
  const float* pe_b2 = (const float*)d_in[9];
  const float* re_w1 = (const float*)d_in[10];
  const float* re_b1 = (const float*)d_in[11];
  const float* re_w2 = (const float*)d_in[12];
  const float* re_b2 = (const float*)d_in[13];
  const float* re_w3 = (const float*)d_in[14];
  const float* re_b3 = (const float*)d_in[15];
  const float* rp_w  = (const float*)d_in[16];
  const float* rp_b  = (const float*)d_in[17];
  const float* pp_w  = (const float*)d_in[18];
  const float* pp_b  = (const float*)d_in[19];
  const float* pr_w1 = (const float*)d_in[20];
  const float* pr_b1 = (const float*)d_in[21];
  const float* pr_w2 = (const float*)d_in[22];
  const float* pr_b2 = (const float*)d_in[23];

  char* w = (char*)d_ws;
  int*   eidx      = (int*)w;   w += (size_t)NODES * KK * 4;
  int*   evalid    = (int*)w;   w += (size_t)NODES * KK * 4;
  float* p_const   = (float*)w; w += (size_t)NODES * 64 * 4;
  float* rel_const = (float*)w; w += (size_t)NODES * KK * 64 * 4;
  float* effA      = (float*)w; w += (size_t)NODES * 64 * 4;
  float* effB      = (float*)w; w += (size_t)NODES * 64 * 4;

  k_edges<<<16, 256, 0, stream>>>(states, maskp, toolp, eidx, evalid);
  k_encode<<<GRID_N, 256, 0, stream>>>(states, a_cur, s_delta,
      pe_w1, pe_b1, pe_w2, pe_b2, re_w1, re_b1, re_w2, re_b2, re_w3, re_b3,
      rp_w, rp_b, pp_w, pp_b, eidx, evalid, p_const, rel_const, effA);
  k_prop<<<GRID_N, 256, 0, stream>>>(rp_w, pp_w, eidx, evalid, p_const, rel_const, effA, effB);
  k_prop<<<GRID_N, 256, 0, stream>>>(rp_w, pp_w, eidx, evalid, p_const, rel_const, effB, effA);
  k_prop<<<GRID_N, 256, 0, stream>>>(rp_w, pp_w, eidx, evalid, p_const, rel_const, effA, effB);
  k_out<<<GRID_N, 256, 0, stream>>>(states, pr_w1, pr_b1, pr_w2, pr_b2, effB, (float*)d_out);
}

// Round 2
// 352.153 us; speedup vs baseline: 2.7038x; 2.7038x over previous
//
#include <hip/hip_runtime.h>
#include <math.h>

#define DEV __device__ __forceinline__

constexpr int B = 2, N = 2048, KK = 8, NF = 64;
constexpr int NODES = B * N;           // 4096
constexpr int GRID_N = NODES / 4;      // 1024 blocks, 4 waves (nodes) per block

// ---- bool input format detection (harness marshalling of jnp bool is unspecified)
DEV int bool_mode(const void* p) {
  unsigned v = *(const unsigned*)p;
  if (v == 0x3f800000u) return 2;      // float32 1.0
  if (v <= 1u) return 1;               // int32 0/1
  return 0;                            // uint8 (0x01010101 for all-true)
}
DEV bool read_mask(const void* p, int i, int mode) {
  if (mode == 2) return ((const float*)p)[i] != 0.f;
  if (mode == 1) return ((const int*)p)[i] != 0;
  return ((const unsigned char*)p)[i] != 0;
}

// sum_k shfl(x,k) * W[k*64+f]  -- 4 accumulators to break the FMA chain
DEV float dot64(float x, const float* W, int f) {
  float a0 = 0.f, a1 = 0.f, a2 = 0.f, a3 = 0.f;
  #pragma unroll
  for (int k = 0; k < 64; k += 4) {
    a0 = fmaf(__shfl(x, k + 0), W[(k + 0) * 64 + f], a0);
    a1 = fmaf(__shfl(x, k + 1), W[(k + 1) * 64 + f], a1);
    a2 = fmaf(__shfl(x, k + 2), W[(k + 2) * 64 + f], a2);
    a3 = fmaf(__shfl(x, k + 3), W[(k + 3) * 64 + f], a3);
  }
  return (a0 + a1) + (a2 + a3);
}

// ---------------- 8-NN edges: one wave per receiver -----------------------------
// Per-lane top-8 insertion over 32 strided candidates, then 6 xor-shuffle bitonic
// merges with lexicographic (dist, idx) compare == exact lax.top_k semantics.
#define LESS(da, ja, db, jb) ((da) < (db) || ((da) == (db) && (ja) < (jb)))
#define CE(a, b)                                                              \
  {                                                                           \
    bool sw_ = LESS(nd[b], nj[b], nd[a], nj[a]);                              \
    float t_ = nd[a]; int u_ = nj[a];                                         \
    if (sw_) { nd[a] = nd[b]; nj[a] = nj[b]; nd[b] = t_; nj[b] = u_; }        \
  }

__global__ __launch_bounds__(256) void k_edges(
    const float* __restrict__ states, const void* maskp, const void* toolp,
    int* __restrict__ eidx, int* __restrict__ evalid) {
  __shared__ float px[N], py[N], pz[N], padd[N];
  const int node0 = blockIdx.x * 4;
  const int b = node0 >> 11;
  const int tid = threadIdx.x;
  const int mm = bool_mode(maskp), mt = bool_mode(toolp);
  for (int j = tid; j < N; j += 256) {
    const float* s = states + (size_t)(b * N + j) * 3;
    px[j] = s[0]; py[j] = s[1]; pz[j] = s[2];
    padd[j] = read_mask(maskp, b * N + j, mm) ? 0.f : 1e10f;
  }
  __syncthreads();
  const int wid = tid >> 6, lane = tid & 63;
  const int node = node0 + wid;
  const int i = node & (N - 1);
  const bool mi = read_mask(maskp, node, mm);
  const bool ti = read_mask(toolp, node, mt);   // tool receivers never get edges
  float td[KK]; int tj[KK];
  #pragma unroll
  for (int k = 0; k < KK; ++k) { td[k] = 3.0e38f; tj[k] = 0; }
  if (mi && !ti) {
    const float sx = px[i], sy = py[i], sz = pz[i];
    #pragma unroll 4
    for (int it = 0; it < N / 64; ++it) {
      int j = lane + it * 64;
      float dx = sx - px[j], dy = sy - py[j], dz = sz - pz[j];
      // no-contract so the adjacency bit matches the reference's f32 math
      float dis = __fadd_rn(__fadd_rn(__fmul_rn(dx, dx), __fmul_rn(dy, dy)),
                            __fmul_rn(dz, dz));
      float dd = __fadd_rn(dis, padd[j]);        // masked pairs -> exactly 1e10
      if (dd < td[KK - 1]) {                     // strict < == stable insertion
        float cd = dd; int cj = j;
        #pragma unroll
        for (int m = 0; m < KK; ++m) {
          bool sw = cd < td[m];
          float od = td[m]; int oj = tj[m];
          td[m] = sw ? cd : od; tj[m] = sw ? cj : oj;
          cd = sw ? od : cd;   cj = sw ? oj : cj;
        }
      }
    }
    #pragma unroll
    for (int m = 1; m < 64; m <<= 1) {
      float pd[KK]; int pj[KK];
      #pragma unroll
      for (int r = 0; r < KK; ++r) {
        pd[r] = __shfl_xor(td[r], m);
        pj[r] = __shfl_xor(tj[r], m);
      }
      float nd[KK]; int nj[KK];
      #pragma unroll
      for (int r = 0; r < KK; ++r) {     // keep 8 smallest (bitonic first stage)
        float ad = td[r]; int aj = tj[r];
        float bd = pd[KK - 1 - r]; int bj = pj[KK - 1 - r];
        bool tb = LESS(bd, bj, ad, aj);
        nd[r] = tb ? bd : ad; nj[r] = tb ? bj : aj;
      }
      CE(0, 4) CE(1, 5) CE(2, 6) CE(3, 7)        // bitonic clean-up sort-8
      CE(0, 2) CE(1, 3) CE(4, 6) CE(5, 7)
      CE(0, 1) CE(2, 3) CE(4, 5) CE(6, 7)
      #pragma unroll
      for (int r = 0; r < KK; ++r) { td[r] = nd[r]; tj[r] = nj[r]; }
    }
  }
  if (lane == 0) {
    const float T2 = (float)(0.12 * 0.12);
    const int base = node * KK;
    const bool ok = mi && !ti;
    #pragma unroll
    for (int k = 0; k < KK; ++k) {
      evalid[base + k] = (ok && td[k] < T2) ? 1 : 0;
      eidx[base + k] = tj[k];
    }
  }
}

// ---------------- particle + relation encoders, step-invariant precomputes ------
__global__ __launch_bounds__(256) void k_encode(
    const float* __restrict__ states, const float* __restrict__ a_cur,
    const float* __restrict__ s_delta,
    const float* __restrict__ pe_w1, const float* __restrict__ pe_b1,
    const float* __restrict__ pe_w2, const float* __restrict__ pe_b2,
    const float* __restrict__ re_w1, const float* __restrict__ re_b1,
    const float* __restrict__ re_w2, const float* __restrict__ re_b2,
    const float* __restrict__ re_w3, const float* __restrict__ re_b3,
    const float* __restrict__ rp_w, const float* __restrict__ rp_b,
    const float* __restrict__ pp_w, const float* __restrict__ pp_b,
    const int* __restrict__ eidx, const int* __restrict__ evalid,
    float* __restrict__ p_const, float* __restrict__ rel_const,
    float* __restrict__ eff0) {
  __shared__ float s_re2[64 * 64], s_re3[64 * 64], s_rp0[64 * 64];
  for (int t = threadIdx.x; t < 64 * 64; t += 256) {
    s_re2[t] = re_w2[t]; s_re3[t] = re_w3[t]; s_rp0[t] = rp_w[t];
  }
  __syncthreads();
  const int node = blockIdx.x * 4 + (threadIdx.x >> 6);
  const int f = threadIdx.x & 63;
  const int b = node >> 11, i = node & (N - 1);
  float a = a_cur[b * N + i];
  float acc = pe_b1[f];
  #pragma unroll
  for (int k = 0; k < 9; ++k) acc = fmaf(s_delta[(b * 9 + k) * N + i], pe_w1[k * 64 + f], acc);
  #pragma unroll
  for (int k = 9; k < 12; ++k) acc = fmaf(a, pe_w1[k * 64 + f], acc);
  float h = fmaxf(acc, 0.f);
  float pe = fmaxf(pe_b2[f] + dot64(h, pe_w2, f), 0.f);
  eff0[node * 64 + f] = pe;
  p_const[node * 64 + f] = pp_b[f] + dot64(pe, pp_w, f);
  const float sx = states[(b * N + i) * 3], sy = states[(b * N + i) * 3 + 1],
              sz = states[(b * N + i) * 3 + 2];
  for (int e = 0; e < KK; ++e) {
    if (!evalid[node * KK + e]) continue;
    int j = eidx[node * KK + e];
    float as = a_cur[b * N + j];
    float dx = sx - states[(b * N + j) * 3];
    float dy = sy - states[(b * N + j) * 3 + 1];
    float dz = sz - states[(b * N + j) * 3 + 2];
    float r = re_b1[f];
    r = fmaf(a,  re_w1[f],       r);
    r = fmaf(as, re_w1[64 + f],  r);
    r = fmaf(dx, re_w1[128 + f], r);
    r = fmaf(dy, re_w1[192 + f], r);
    r = fmaf(dz, re_w1[256 + f], r);
    float h1 = fmaxf(r, 0.f);
    float h2 = fmaxf(re_b2[f] + dot64(h1, s_re2, f), 0.f);
    float h3 = fmaxf(re_b3[f] + dot64(h2, s_re3, f), 0.f);
    rel_const[(node * KK + e) * 64 + f] = rp_b[f] + dot64(h3, s_rp0, f);
  }
}

// ---------------- one propagation step (ping-pong effect buffers) ---------------
__global__ __launch_bounds__(256) void k_prop(
    const float* __restrict__ rp_w, const float* __restrict__ pp_w,
    const int* __restrict__ eidx, const int* __restrict__ evalid,
    const float* __restrict__ p_const, const float* __restrict__ rel_const,
    const float* __restrict__ effIn, float* __restrict__ effOut) {
  __shared__ float s_rp1[64 * 64], s_rp2[64 * 64], s_pp1[64 * 64];
  for (int t = threadIdx.x; t < 64 * 64; t += 256) {
    s_rp1[t] = rp_w[64 * 64 + t];        // rows 64..127  (eff_r)
    s_rp2[t] = rp_w[2 * 64 * 64 + t];    // rows 128..191 (eff_s)
    s_pp1[t] = pp_w[64 * 64 + t];        // rows 64..127  (agg)
  }
  __syncthreads();
  const int node = blockIdx.x * 4 + (threadIdx.x >> 6);
  const int f = threadIdx.x & 63;
  const int nb = node & ~(N - 1);
  float effR = effIn[node * 64 + f];
  float w1eff = dot64(effR, s_rp1, f);   // edge-invariant: hoisted out of e-loop
  float agg = 0.f;
  for (int e = 0; e < KK; ++e) {
    if (!evalid[node * KK + e]) continue;
    int j = eidx[node * KK + e];
    float effS = effIn[(nb + j) * 64 + f];
    float acc = rel_const[(node * KK + e) * 64 + f];
    acc += w1eff;
    acc += dot64(effS, s_rp2, f);
    agg += fmaxf(acc, 0.f);
  }
  float o = p_const[node * 64 + f] + dot64(agg, s_pp1, f);
  effOut[node * 64 + f] = fmaxf(o + effR, 0.f);
}

// ---------------- predictor head + residual add --------------------------------
__global__ __launch_bounds__(256) void k_out(
    const float* __restrict__ states,
    const float* __restrict__ pr_w1, const float* __restrict__ pr_b1,
    const float* __restrict__ pr_w2, const float* __restrict__ pr_b2,
    const float* __restrict__ eff, float* __restrict__ out) {
  const int node = blockIdx.x * 4 + (threadIdx.x >> 6);
  const int f = threadIdx.x & 63;
  float e = eff[node * 64 + f];
  float h = fmaxf(pr_b1[f] + dot64(e, pr_w1, f), 0.f);
  #pragma unroll
  for (int d = 0; d < 3; ++d) {
    float v = h * pr_w2[f * 3 + d];
    #pragma unroll
    for (int o = 32; o > 0; o >>= 1) v += __shfl_xor(v, o);
    if (f == 0) out[node * 3 + d] = states[node * 3 + d] + v + pr_b2[d];
  }
}

extern "C" void kernel_launch(void* const* d_in, const int* in_sizes, int n_in,
                              void* d_out, int out_size, void* d_ws, size_t ws_size,
                              hipStream_t stream) {
  const float* states  = (const float*)d_in[0];
  const float* a_cur   = (const float*)d_in[1];
  const float* s_delta = (const float*)d_in[2];
  const void*  maskp   = d_in[3];
  const void*  toolp   = d_in[4];
  const float* pe_w1 = (const float*)d_in[6];
  const float* pe_b1 = (const float*)d_in[7];
  const float* pe_w2 = (const float*)d_in[8];
  const float* pe_b2 = (const float*)d_in[9];
  const float* re_w1 = (const float*)d_in[10];
  const float* re_b1 = (const float*)d_in[11];
  const float* re_w2 = (const float*)d_in[12];
  const float* re_b2 = (const float*)d_in[13];
  const float* re_w3 = (const float*)d_in[14];
  const float* re_b3 = (const float*)d_in[15];
  const float* rp_w  = (const float*)d_in[16];
  const float* rp_b  = (const float*)d_in[17];
  const float* pp_w  = (const float*)d_in[18];
  const float* pp_b  = (const float*)d_in[19];
  const float* pr_w1 = (const float*)d_in[20];
  const float* pr_b1 = (const float*)d_in[21];
  const float* pr_w2 = (const float*)d_in[22];
  const float* pr_b2 = (const float*)d_in[23];

  char* w = (char*)d_ws;
  int*   eidx      = (int*)w;   w += (size_t)NODES * KK * 4;
  int*   evalid    = (int*)w;   w += (size_t)NODES * KK * 4;
  float* p_const   = (float*)w; w += (size_t)NODES * 64 * 4;
  float* rel_const = (float*)w; w += (size_t)NODES * KK * 64 * 4;
  float* effA      = (float*)w; w += (size_t)NODES * 64 * 4;
  float* effB      = (float*)w; w += (size_t)NODES * 64 * 4;

  k_edges<<<GRID_N, 256, 0, stream>>>(states, maskp, toolp, eidx, evalid);
  k_encode<<<GRID_N, 256, 0, stream>>>(states, a_cur, s_delta,
      pe_w1, pe_b1, pe_w2, pe_b2, re_w1, re_b1, re_w2, re_b2, re_w3, re_b3,
      rp_w, rp_b, pp_w, pp_b, eidx, evalid, p_const, rel_const, effA);
  k_prop<<<GRID_N, 256, 0, stream>>>(rp_w, pp_w, eidx, evalid, p_const, rel_const, effA, effB);
  k_prop<<<GRID_N, 256, 0, stream>>>(rp_w, pp_w, eidx, evalid, p_const, rel_const, effB, effA);
  k_prop<<<GRID_N, 256, 0, stream>>>(rp_w, pp_w, eidx, evalid, p_const, rel_const, effA, effB);
  k_out<<<GRID_N, 256, 0, stream>>>(states, pr_w1, pr_b1, pr_w2, pr_b2, effB, (float*)d_out);
}

// Round 3
// 268.884 us; speedup vs baseline: 3.5412x; 1.3097x over previous
//
#include <hip/hip_runtime.h>
#include <math.h>

#define DEV __device__ __forceinline__

constexpr int B = 2, N = 2048, KK = 8, NF = 64;
constexpr int NODES = B * N;           // 4096
constexpr int NSLOTS = NODES * KK;     // 32768

// ---- bool input format detection (harness marshalling of jnp bool is unspecified)
DEV int bool_mode(const void* p) {
  unsigned v = *(const unsigned*)p;
  if (v == 0x3f800000u) return 2;      // float32 1.0
  if (v <= 1u) return 1;               // int32 0/1
  return 0;                            // uint8
}
DEV bool read_mask(const void* p, int i, int mode) {
  if (mode == 2) return ((const float*)p)[i] != 0.f;
  if (mode == 1) return ((const int*)p)[i] != 0;
  return ((const unsigned char*)p)[i] != 0;
}

// ================= 8-NN edges (unchanged from R2 — proven) =====================
#define LESS(da, ja, db, jb) ((da) < (db) || ((da) == (db) && (ja) < (jb)))
#define CE(a, b)                                                              \
  {                                                                           \
    bool sw_ = LESS(nd[b], nj[b], nd[a], nj[a]);                              \
    float t_ = nd[a]; int u_ = nj[a];                                         \
    if (sw_) { nd[a] = nd[b]; nj[a] = nj[b]; nd[b] = t_; nj[b] = u_; }        \
  }

__global__ __launch_bounds__(256) void k_edges(
    const float* __restrict__ states, const void* maskp, const void* toolp,
    int* __restrict__ eidx, int* __restrict__ evalid) {
  __shared__ float px[N], py[N], pz[N], padd[N];
  const int node0 = blockIdx.x * 4;
  const int b = node0 >> 11;
  const int tid = threadIdx.x;
  const int mm = bool_mode(maskp), mt = bool_mode(toolp);
  for (int j = tid; j < N; j += 256) {
    const float* s = states + (size_t)(b * N + j) * 3;
    px[j] = s[0]; py[j] = s[1]; pz[j] = s[2];
    padd[j] = read_mask(maskp, b * N + j, mm) ? 0.f : 1e10f;
  }
  __syncthreads();
  const int wid = tid >> 6, lane = tid & 63;
  const int node = node0 + wid;
  const int i = node & (N - 1);
  const bool mi = read_mask(maskp, node, mm);
  const bool ti = read_mask(toolp, node, mt);
  float td[KK]; int tj[KK];
  #pragma unroll
  for (int k = 0; k < KK; ++k) { td[k] = 3.0e38f; tj[k] = 0; }
  if (mi && !ti) {
    const float sx = px[i], sy = py[i], sz = pz[i];
    #pragma unroll 4
    for (int it = 0; it < N / 64; ++it) {
      int j = lane + it * 64;
      float dx = sx - px[j], dy = sy - py[j], dz = sz - pz[j];
      float dis = __fadd_rn(__fadd_rn(__fmul_rn(dx, dx), __fmul_rn(dy, dy)),
                            __fmul_rn(dz, dz));
      float dd = __fadd_rn(dis, padd[j]);
      if (dd < td[KK - 1]) {
        float cd = dd; int cj = j;
        #pragma unroll
        for (int m = 0; m < KK; ++m) {
          bool sw = cd < td[m];
          float od = td[m]; int oj = tj[m];
          td[m] = sw ? cd : od; tj[m] = sw ? cj : oj;
          cd = sw ? od : cd;   cj = sw ? oj : cj;
        }
      }
    }
    #pragma unroll
    for (int m = 1; m < 64; m <<= 1) {
      float pd[KK]; int pj[KK];
      #pragma unroll
      for (int r = 0; r < KK; ++r) {
        pd[r] = __shfl_xor(td[r], m);
        pj[r] = __shfl_xor(tj[r], m);
      }
      float nd[KK]; int nj[KK];
      #pragma unroll
      for (int r = 0; r < KK; ++r) {
        float ad = td[r]; int aj = tj[r];
        float bd = pd[KK - 1 - r]; int bj = pj[KK - 1 - r];
        bool tb = LESS(bd, bj, ad, aj);
        nd[r] = tb ? bd : ad; nj[r] = tb ? bj : aj;
      }
      CE(0, 4) CE(1, 5) CE(2, 6) CE(3, 7)
      CE(0, 2) CE(1, 3) CE(4, 6) CE(5, 7)
      CE(0, 1) CE(2, 3) CE(4, 5) CE(6, 7)
      #pragma unroll
      for (int r = 0; r < KK; ++r) { td[r] = nd[r]; tj[r] = nj[r]; }
    }
  }
  if (lane == 0) {
    const float T2 = (float)(0.12 * 0.12);
    const int base = node * KK;
    const bool ok = mi && !ti;
    #pragma unroll
    for (int k = 0; k < KK; ++k) {
      evalid[base + k] = (ok && td[k] < T2) ? 1 : 0;
      eidx[base + k] = tj[k];
    }
  }
}

// ================= shared MLP primitives =======================================
// LDS layout: act[k][col], k=0..63 activation index, col=0..63 edge/node in block.
// stage32: lane writes its 32-feature half (frow0..frow0+31) of column `col`.
DEV void stage32(float* lds, int col, int frow0, const float* h) {
  #pragma unroll
  for (int u = 0; u < 32; ++u) lds[(frow0 + u) * 64 + col] = h[u];
}
// mv32: acc[u] += sum_k lds[k][col] * W[k*64 + u], W wave-uniform (SGPR broadcast)
DEV void mv32(float* acc, const float* __restrict__ W, const float* lds, int col) {
  for (int k = 0; k < 64; ++k) {
    float hk = lds[k * 64 + col];
    const float* Wr = W + k * 64;
    #pragma unroll
    for (int u = 0; u < 32; ++u) acc[u] = fmaf(hk, Wr[u], acc[u]);
  }
}
DEV void load32(float* r, const float* __restrict__ g) {
  #pragma unroll
  for (int q = 0; q < 8; ++q) {
    float4 v = ((const float4*)g)[q];
    r[4 * q] = v.x; r[4 * q + 1] = v.y; r[4 * q + 2] = v.z; r[4 * q + 3] = v.w;
  }
}
DEV void store32(float* __restrict__ g, const float* r) {
  #pragma unroll
  for (int q = 0; q < 8; ++q) {
    float4 v; v.x = r[4 * q]; v.y = r[4 * q + 1]; v.z = r[4 * q + 2]; v.w = r[4 * q + 3];
    ((float4*)g)[q] = v;
  }
}

// ================= node encoder: p_enc + p_const ===============================
// 128 threads = 64 nodes x 2 f-halves (half per wave -> uniform W addresses).
__global__ __launch_bounds__(128) void k_enc_node(
    const float* __restrict__ a_cur, const float* __restrict__ s_delta,
    const float* __restrict__ pe_w1, const float* __restrict__ pe_b1,
    const float* __restrict__ pe_w2, const float* __restrict__ pe_b2,
    const float* __restrict__ pp_w, const float* __restrict__ pp_b,
    float* __restrict__ p_const, float* __restrict__ eff0) {
  __shared__ float lds[64 * 64];
  const int lane = threadIdx.x & 63;
  const int half0 = __builtin_amdgcn_readfirstlane((threadIdx.x >> 6) << 5);
  const int node = blockIdx.x * 64 + lane;
  const int b = node >> 11, i = node & (N - 1);
  float sd[9];
  #pragma unroll
  for (int k = 0; k < 9; ++k) sd[k] = s_delta[(b * 9 + k) * N + i];
  const float a = a_cur[node];
  float h[32];
  #pragma unroll
  for (int u = 0; u < 32; ++u) {
    const int f = half0 + u;
    float x = pe_b1[f];
    #pragma unroll
    for (int k = 0; k < 9; ++k) x = fmaf(sd[k], pe_w1[k * 64 + f], x);
    x = fmaf(a, pe_w1[9 * 64 + f] + pe_w1[10 * 64 + f] + pe_w1[11 * 64 + f], x);
    h[u] = fmaxf(x, 0.f);
  }
  stage32(lds, lane, half0, h);
  __syncthreads();
  #pragma unroll
  for (int u = 0; u < 32; ++u) h[u] = pe_b2[half0 + u];
  mv32(h, pe_w2 + half0, lds, lane);
  #pragma unroll
  for (int u = 0; u < 32; ++u) h[u] = fmaxf(h[u], 0.f);
  store32(eff0 + (size_t)node * 64 + half0, h);
  __syncthreads();
  stage32(lds, lane, half0, h);
  __syncthreads();
  #pragma unroll
  for (int u = 0; u < 32; ++u) h[u] = pp_b[half0 + u];
  mv32(h, pp_w + half0, lds, lane);          // pp_w rows 0..63 (p_enc part)
  store32(p_const + (size_t)node * 64 + half0, h);
}

// ================= edge encoder: rel_const per slot ============================
// 128 threads = 64 edge slots x 2 f-halves.
__global__ __launch_bounds__(128) void k_enc_edge(
    const float* __restrict__ states, const float* __restrict__ a_cur,
    const float* __restrict__ re_w1, const float* __restrict__ re_b1,
    const float* __restrict__ re_w2, const float* __restrict__ re_b2,
    const float* __restrict__ re_w3, const float* __restrict__ re_b3,
    const float* __restrict__ rp_w, const float* __restrict__ rp_b,
    const int* __restrict__ eidx, const int* __restrict__ evalid,
    float* __restrict__ rel_const) {
  __shared__ float lds[64 * 64];
  const int lane = threadIdx.x & 63;
  const int half0 = __builtin_amdgcn_readfirstlane((threadIdx.x >> 6) << 5);
  const int slot = blockIdx.x * 64 + lane;
  const int node = slot >> 3;
  const int nb = node & ~(N - 1);
  const int j = nb + eidx[slot];
  const float a_r = a_cur[node], a_s = a_cur[j];
  const float dx = states[node * 3]     - states[j * 3];
  const float dy = states[node * 3 + 1] - states[j * 3 + 1];
  const float dz = states[node * 3 + 2] - states[j * 3 + 2];
  float h[32];
  #pragma unroll
  for (int u = 0; u < 32; ++u) {
    const int f = half0 + u;
    float x = re_b1[f];
    x = fmaf(a_r, re_w1[f], x);
    x = fmaf(a_s, re_w1[64 + f], x);
    x = fmaf(dx, re_w1[128 + f], x);
    x = fmaf(dy, re_w1[192 + f], x);
    x = fmaf(dz, re_w1[256 + f], x);
    h[u] = fmaxf(x, 0.f);
  }
  stage32(lds, lane, half0, h);
  __syncthreads();
  #pragma unroll
  for (int u = 0; u < 32; ++u) h[u] = re_b2[half0 + u];
  mv32(h, re_w2 + half0, lds, lane);
  #pragma unroll
  for (int u = 0; u < 32; ++u) h[u] = fmaxf(h[u], 0.f);
  __syncthreads();
  stage32(lds, lane, half0, h);
  __syncthreads();
  #pragma unroll
  for (int u = 0; u < 32; ++u) h[u] = re_b3[half0 + u];
  mv32(h, re_w3 + half0, lds, lane);
  #pragma unroll
  for (int u = 0; u < 32; ++u) h[u] = fmaxf(h[u], 0.f);
  __syncthreads();
  stage32(lds, lane, half0, h);
  __syncthreads();
  #pragma unroll
  for (int u = 0; u < 32; ++u) h[u] = rp_b[half0 + u];
  mv32(h, rp_w + half0, lds, lane);          // rp_w rows 0..63 (rel_enc part)
  const float v = evalid[slot] ? 1.f : 0.f;  // zero invalid so k_prop adds nothing
  #pragma unroll
  for (int u = 0; u < 32; ++u) h[u] *= v;
  store32(rel_const + (size_t)slot * 64 + half0, h);
}

// ================= one propagation step ========================================
// 128 threads = 64 slots (8 nodes) x 2 f-halves.
__global__ __launch_bounds__(128) void k_prop(
    const float* __restrict__ rp_w, const float* __restrict__ pp_w,
    const int* __restrict__ eidx, const int* __restrict__ evalid,
    const float* __restrict__ p_const, const float* __restrict__ rel_const,
    const float* __restrict__ effIn, float* __restrict__ effOut) {
  __shared__ float lds[64 * 64];
  __shared__ float agg_lds[64 * 8];
  const int tid = threadIdx.x;
  const int lane = tid & 63;
  const int half0 = __builtin_amdgcn_readfirstlane((tid >> 6) << 5);
  const int slot0 = blockIdx.x * 64;
  const int slot = slot0 + lane;
  const int node = slot >> 3;
  const int nb = node & ~(N - 1);
  const int j = nb + eidx[slot];
  float r[32];
  load32(r, effIn + (size_t)node * 64 + half0);     // eff_r (receiver)
  stage32(lds, lane, half0, r);
  __syncthreads();
  float t[32];
  load32(t, rel_const + (size_t)slot * 64 + half0);
  mv32(t, rp_w + 64 * 64 + half0, lds, lane);       // rows 64..127: eff_r term
  __syncthreads();
  load32(r, effIn + (size_t)j * 64 + half0);        // eff_s (sender)
  stage32(lds, lane, half0, r);
  __syncthreads();
  mv32(t, rp_w + 2 * 64 * 64 + half0, lds, lane);   // rows 128..191: eff_s term
  const float v = evalid[slot] ? 1.f : 0.f;
  #pragma unroll
  for (int u = 0; u < 32; ++u) {
    float x = fmaxf(t[u], 0.f) * v;                 // relu(rel_eff) * valid
    x += __shfl_xor(x, 1);                          // sum 8 slots of this node
    x += __shfl_xor(x, 2);
    x += __shfl_xor(x, 4);
    t[u] = x;                                       // agg[f], replicated
  }
  const int nl = lane >> 3, rr = lane & 7;
  #pragma unroll
  for (int q = 0; q < 4; ++q)
    agg_lds[(half0 + rr * 4 + q) * 8 + nl] = t[rr * 4 + q];
  __syncthreads();
  // pp1 matvec: 128 threads -> 8 nodes x 16 lanes x 4 outputs
  const int pn = tid >> 4, f0 = (tid & 15) * 4;
  const int onode = (slot0 >> 3) + pn;
  float o[4];
  {
    float4 pc = *(const float4*)(p_const + (size_t)onode * 64 + f0);
    o[0] = pc.x; o[1] = pc.y; o[2] = pc.z; o[3] = pc.w;
  }
  #pragma unroll
  for (int g = 0; g < 64; ++g) {
    float ag = agg_lds[g * 8 + pn];
    float4 wv = *(const float4*)(pp_w + 64 * 64 + g * 64 + f0);
    o[0] = fmaf(ag, wv.x, o[0]); o[1] = fmaf(ag, wv.y, o[1]);
    o[2] = fmaf(ag, wv.z, o[2]); o[3] = fmaf(ag, wv.w, o[3]);
  }
  float4 er = *(const float4*)(effIn + (size_t)onode * 64 + f0);
  float4 ov;
  ov.x = fmaxf(o[0] + er.x, 0.f);
  ov.y = fmaxf(o[1] + er.y, 0.f);
  ov.z = fmaxf(o[2] + er.z, 0.f);
  ov.w = fmaxf(o[3] + er.w, 0.f);
  *(float4*)(effOut + (size_t)onode * 64 + f0) = ov;
}

// ================= predictor head + residual ===================================
__global__ __launch_bounds__(128) void k_out(
    const float* __restrict__ states,
    const float* __restrict__ pr_w1, const float* __restrict__ pr_b1,
    const float* __restrict__ pr_w2, const float* __restrict__ pr_b2,
    const float* __restrict__ eff, float* __restrict__ out) {
  __shared__ float lds[64 * 64];
  __shared__ float part[2][64][3];
  const int w = threadIdx.x >> 6, lane = threadIdx.x & 63;
  const int half0 = __builtin_amdgcn_readfirstlane(w << 5);
  const int node = blockIdx.x * 64 + lane;
  float r[32];
  load32(r, eff + (size_t)node * 64 + half0);
  stage32(lds, lane, half0, r);
  __syncthreads();
  float t[32];
  #pragma unroll
  for (int u = 0; u < 32; ++u) t[u] = pr_b1[half0 + u];
  mv32(t, pr_w1 + half0, lds, lane);
  float p0 = 0.f, p1 = 0.f, p2 = 0.f;
  #pragma unroll
  for (int u = 0; u < 32; ++u) {
    float hh = fmaxf(t[u], 0.f);
    const int f = half0 + u;
    p0 = fmaf(hh, pr_w2[f * 3 + 0], p0);
    p1 = fmaf(hh, pr_w2[f * 3 + 1], p1);
    p2 = fmaf(hh, pr_w2[f * 3 + 2], p2);
  }
  part[w][lane][0] = p0; part[w][lane][1] = p1; part[w][lane][2] = p2;
  __syncthreads();
  if (w == 0) {
    #pragma unroll
    for (int d = 0; d < 3; ++d)
      out[node * 3 + d] = states[node * 3 + d] + part[0][lane][d] +
                          part[1][lane][d] + pr_b2[d];
  }
}

extern "C" void kernel_launch(void* const* d_in, const int* in_sizes, int n_in,
                              void* d_out, int out_size, void* d_ws, size_t ws_size,
                              hipStream_t stream) {
  const float* states  = (const float*)d_in[0];
  const float* a_cur   = (const float*)d_in[1];
  const float* s_delta = (const float*)d_in[2];
  const void*  maskp   = d_in[3];
  const void*  toolp   = d_in[4];
  const float* pe_w1 = (const float*)d_in[6];
  const float* pe_b1 = (const float*)d_in[7];
  const float* pe_w2 = (const float*)d_in[8];
  const float* pe_b2 = (const float*)d_in[9];
  const float* re_w1 = (const float*)d_in[10];
  const float* re_b1 = (const float*)d_in[11];
  const float* re_w2 = (const float*)d_in[12];
  const float* re_b2 = (const float*)d_in[13];
  const float* re_w3 = (const float*)d_in[14];
  const float* re_b3 = (const float*)d_in[15];
  const float* rp_w  = (const float*)d_in[16];
  const float* rp_b  = (const float*)d_in[17];
  const float* pp_w  = (const float*)d_in[18];
  const float* pp_b  = (const float*)d_in[19];
  const float* pr_w1 = (const float*)d_in[20];
  const float* pr_b1 = (const float*)d_in[21];
  const float* pr_w2 = (const float*)d_in[22];
  const float* pr_b2 = (const float*)d_in[23];

  char* w = (char*)d_ws;
  int*   eidx      = (int*)w;   w += (size_t)NSLOTS * 4;
  int*   evalid    = (int*)w;   w += (size_t)NSLOTS * 4;
  float* p_const   = (float*)w; w += (size_t)NODES * 64 * 4;
  float* rel_const = (float*)w; w += (size_t)NSLOTS * 64 * 4;
  float* effA      = (float*)w; w += (size_t)NODES * 64 * 4;
  float* effB      = (float*)w; w += (size_t)NODES * 64 * 4;

  k_edges<<<NODES / 4, 256, 0, stream>>>(states, maskp, toolp, eidx, evalid);
  k_enc_node<<<NODES / 64, 128, 0, stream>>>(a_cur, s_delta, pe_w1, pe_b1,
      pe_w2, pe_b2, pp_w, pp_b, p_const, effA);
  k_enc_edge<<<NSLOTS / 64, 128, 0, stream>>>(states, a_cur,
      re_w1, re_b1, re_w2, re_b2, re_w3, re_b3, rp_w, rp_b,
      eidx, evalid, rel_const);
  k_prop<<<NSLOTS / 64, 128, 0, stream>>>(rp_w, pp_w, eidx, evalid, p_const,
      rel_const, effA, effB);
  k_prop<<<NSLOTS / 64, 128, 0, stream>>>(rp_w, pp_w, eidx, evalid, p_const,
      rel_const, effB, effA);
  k_prop<<<NSLOTS / 64, 128, 0, stream>>>(rp_w, pp_w, eidx, evalid, p_const,
      rel_const, effA, effB);
  k_out<<<NODES / 64, 128, 0, stream>>>(states, pr_w1, pr_b1, pr_w2, pr_b2,
      effB, (float*)d_out);
}

// Round 5
// 191.826 us; speedup vs baseline: 4.9637x; 1.4017x over previous
//
#include <hip/hip_runtime.h>
#include <math.h>

#define DEV __device__ __forceinline__

constexpr int BB = 2, N = 2048, KK = 8;
constexpr int NODES = BB * N;          // 4096
constexpr int NSLOTS = NODES * KK;     // 32768
constexpr int NPB = 8;                 // nodes per block
constexpr int TPB = 512;               // 8 waves
constexpr int NBLK = NODES / NPB;      // 512 blocks

// ---- bool input format detection ----
DEV int bool_mode(const void* p) {
  unsigned v = *(const unsigned*)p;
  if (v == 0x3f800000u) return 2;      // float32 1.0
  if (v <= 1u) return 1;               // int32 0/1
  return 0;                            // uint8
}
DEV bool read_mask(const void* p, int i, int mode) {
  if (mode == 2) return ((const float*)p)[i] != 0.f;
  if (mode == 1) return ((const int*)p)[i] != 0;
  return ((const unsigned char*)p)[i] != 0;
}

// ---- eighth-split MLP primitives: wave owns feats [f0,f0+8), col = slot in blk.
// act stride 65 (pad): reads 2-way free, stage writes bank-rotated.
DEV void mv8(float* acc, const float* __restrict__ W, const float* act, int col) {
  #pragma unroll 4
  for (int k = 0; k < 64; ++k) {
    float hk = act[k * 65 + col];
    #pragma unroll
    for (int u = 0; u < 8; ++u) acc[u] = fmaf(hk, W[k * 64 + u], acc[u]);
  }
}
DEV void stage8(float* act, int col, int f0, const float* t) {
  #pragma unroll
  for (int u = 0; u < 8; ++u) act[(f0 + u) * 65 + col] = t[u];
}
DEV void load8(float* t, const float* __restrict__ g) {
  float4 v0 = ((const float4*)g)[0], v1 = ((const float4*)g)[1];
  t[0] = v0.x; t[1] = v0.y; t[2] = v0.z; t[3] = v0.w;
  t[4] = v1.x; t[5] = v1.y; t[6] = v1.z; t[7] = v1.w;
}
DEV void store8(float* __restrict__ g, const float* t) {
  ((float4*)g)[0] = make_float4(t[0], t[1], t[2], t[3]);
  ((float4*)g)[1] = make_float4(t[4], t[5], t[6], t[7]);
}

#define LESS(da, ja, db, jb) ((da) < (db) || ((da) == (db) && (ja) < (jb)))
#define CE(a, b)                                                              \
  {                                                                           \
    bool sw_ = LESS(nd[b], nj[b], nd[a], nj[a]);                              \
    float t_ = nd[a]; int u_ = nj[a];                                         \
    if (sw_) { nd[a] = nd[b]; nj[a] = nj[b]; nd[b] = t_; nj[b] = u_; }        \
  }

struct SEdge { float px[N], py[N], pz[N], padd[N]; };   // 32 KB
struct SMlp  { float act[64 * 65]; };                   // 16.6 KB
union SU { SEdge e; SMlp m; };

// ================= K1: edges + node encoder + edge encoder =====================
__global__ __launch_bounds__(TPB, 4) void k_front(
    const float* __restrict__ states, const void* maskp, const void* toolp,
    const float* __restrict__ a_cur, const float* __restrict__ s_delta,
    const float* __restrict__ pe_w1, const float* __restrict__ pe_b1,
    const float* __restrict__ pe_w2, const float* __restrict__ pe_b2,
    const float* __restrict__ re_w1, const float* __restrict__ re_b1,
    const float* __restrict__ re_w2, const float* __restrict__ re_b2,
    const float* __restrict__ re_w3, const float* __restrict__ re_b3,
    const float* __restrict__ rp_w, const float* __restrict__ rp_b,
    const float* __restrict__ pp_w, const float* __restrict__ pp_b,
    int* __restrict__ eidx, float* __restrict__ evalid,
    float* __restrict__ p_const, float* __restrict__ rel_const,
    float* __restrict__ eff0) {
  __shared__ SU sm;
  __shared__ int   sl_idx[64];
  __shared__ float sl_val[64];
  const int tid = threadIdx.x;
  const int wav = tid >> 6, lane = tid & 63;
  const int blk = blockIdx.x;
  const int node0 = blk * NPB;
  const int b = node0 >> 11;
  const int mm = bool_mode(maskp), mt = bool_mode(toolp);

  // ---------- phase 1: 8-NN edges, one node per wave (proven R2/R3 scan) ------
  {
    for (int j = tid; j < N; j += TPB) {
      const float* s = states + (size_t)(b * N + j) * 3;
      sm.e.px[j] = s[0]; sm.e.py[j] = s[1]; sm.e.pz[j] = s[2];
      sm.e.padd[j] = read_mask(maskp, b * N + j, mm) ? 0.f : 1e10f;
    }
    __syncthreads();
    const int node = node0 + wav;
    const int i = node & (N - 1);
    const bool mi = read_mask(maskp, node, mm);
    const bool ti = read_mask(toolp, node, mt);   // tool receivers: no edges
    float td[KK]; int tj[KK];
    #pragma unroll
    for (int k = 0; k < KK; ++k) { td[k] = 3.0e38f; tj[k] = 0; }
    if (mi && !ti) {
      const float sx = sm.e.px[i], sy = sm.e.py[i], sz = sm.e.pz[i];
      #pragma unroll 4
      for (int it = 0; it < N / 64; ++it) {
        int j = lane + it * 64;
        float dx = sx - sm.e.px[j], dy = sy - sm.e.py[j], dz = sz - sm.e.pz[j];
        float dis = __fadd_rn(__fadd_rn(__fmul_rn(dx, dx), __fmul_rn(dy, dy)),
                              __fmul_rn(dz, dz));
        float dd = __fadd_rn(dis, sm.e.padd[j]);    // masked -> exactly 1e10
        if (dd < td[KK - 1]) {                      // strict < == stable
          float cd = dd; int cj = j;
          #pragma unroll
          for (int m = 0; m < KK; ++m) {
            bool sw = cd < td[m];
            float od = td[m]; int oj = tj[m];
            td[m] = sw ? cd : od; tj[m] = sw ? cj : oj;
            cd = sw ? od : cd;   cj = sw ? oj : cj;
          }
        }
      }
      #pragma unroll
      for (int m = 1; m < 64; m <<= 1) {
        float pd[KK]; int pj[KK];
        #pragma unroll
        for (int r = 0; r < KK; ++r) {
          pd[r] = __shfl_xor(td[r], m);
          pj[r] = __shfl_xor(tj[r], m);
        }
        float nd[KK]; int nj[KK];
        #pragma unroll
        for (int r = 0; r < KK; ++r) {
          float ad = td[r]; int aj = tj[r];
          float bd = pd[KK - 1 - r]; int bj = pj[KK - 1 - r];
          bool tb = LESS(bd, bj, ad, aj);
          nd[r] = tb ? bd : ad; nj[r] = tb ? bj : aj;
        }
        CE(0, 4) CE(1, 5) CE(2, 6) CE(3, 7)
        CE(0, 2) CE(1, 3) CE(4, 6) CE(5, 7)
        CE(0, 1) CE(2, 3) CE(4, 5) CE(6, 7)
        #pragma unroll
        for (int r = 0; r < KK; ++r) { td[r] = nd[r]; tj[r] = nj[r]; }
      }
    }
    if (lane == 0) {
      const float T2 = (float)(0.12 * 0.12);
      const bool ok = mi && !ti;
      #pragma unroll
      for (int k = 0; k < KK; ++k) {
        float v = (ok && td[k] < T2) ? 1.f : 0.f;
        sl_idx[wav * KK + k] = tj[k];
        sl_val[wav * KK + k] = v;
        eidx[node * KK + k] = tj[k];
        evalid[node * KK + k] = v;
      }
    }
    __syncthreads();
  }

  // ---------- phase 2: node encoder (wave = node, lane = feature) -------------
  {
    float* hb = sm.m.act;                 // reused, stride 9
    const int nd = node0 + wav;
    const int i = nd & (N - 1);
    const int f = lane;
    float sd[9];
    #pragma unroll
    for (int k = 0; k < 9; ++k) sd[k] = s_delta[(b * 9 + k) * N + i];
    const float a = a_cur[nd];
    float x = pe_b1[f];
    #pragma unroll
    for (int k = 0; k < 9; ++k) x = fmaf(sd[k], pe_w1[k * 64 + f], x);
    x = fmaf(a, pe_w1[576 + f] + pe_w1[640 + f] + pe_w1[704 + f], x);
    x = fmaxf(x, 0.f);
    hb[f * 9 + wav] = x;
    __syncthreads();
    float y = pe_b2[f];
    #pragma unroll 4
    for (int k = 0; k < 64; ++k) y = fmaf(hb[k * 9 + wav], pe_w2[k * 64 + f], y);
    y = fmaxf(y, 0.f);
    eff0[(size_t)nd * 64 + f] = y;        // p_enc == initial effect
    __syncthreads();
    hb[f * 9 + wav] = y;
    __syncthreads();
    float z = pp_b[f];
    #pragma unroll 4
    for (int k = 0; k < 64; ++k) z = fmaf(hb[k * 9 + wav], pp_w[k * 64 + f], z);
    p_const[(size_t)nd * 64 + f] = z;     // pp_b + p_enc @ pp_w[0:64]
    __syncthreads();
  }

  // ---------- phase 3: edge encoder (eighth-split over 64 slots) --------------
  {
    float* act = sm.m.act;                // stride 65
    const int f0 = __builtin_amdgcn_readfirstlane(wav * 8);
    const int col = lane;
    const int slot = blk * 64 + col;
    const int nd = node0 + (col >> 3);
    const int nb = nd & ~(N - 1);
    const int j = nb + sl_idx[col];
    const float a_r = a_cur[nd], a_s = a_cur[j];
    const float dx = states[nd * 3]     - states[j * 3];
    const float dy = states[nd * 3 + 1] - states[j * 3 + 1];
    const float dz = states[nd * 3 + 2] - states[j * 3 + 2];
    float t[8];
    #pragma unroll
    for (int u = 0; u < 8; ++u) {
      const int f = f0 + u;
      float x = re_b1[f];
      x = fmaf(a_r, re_w1[f], x);
      x = fmaf(a_s, re_w1[64 + f], x);
      x = fmaf(dx, re_w1[128 + f], x);
      x = fmaf(dy, re_w1[192 + f], x);
      x = fmaf(dz, re_w1[256 + f], x);
      t[u] = fmaxf(x, 0.f);
    }
    stage8(act, col, f0, t);
    __syncthreads();
    #pragma unroll
    for (int u = 0; u < 8; ++u) t[u] = re_b2[f0 + u];
    mv8(t, re_w2 + f0, act, col);
    #pragma unroll
    for (int u = 0; u < 8; ++u) t[u] = fmaxf(t[u], 0.f);
    __syncthreads();
    stage8(act, col, f0, t);
    __syncthreads();
    #pragma unroll
    for (int u = 0; u < 8; ++u) t[u] = re_b3[f0 + u];
    mv8(t, re_w3 + f0, act, col);
    #pragma unroll
    for (int u = 0; u < 8; ++u) t[u] = fmaxf(t[u], 0.f);
    __syncthreads();
    stage8(act, col, f0, t);
    __syncthreads();
    #pragma unroll
    for (int u = 0; u < 8; ++u) t[u] = rp_b[f0 + u];
    mv8(t, rp_w + f0, act, col);          // rows 0..63 (rel_enc part)
    const float v = sl_val[col];          // zero invalid slots
    #pragma unroll
    for (int u = 0; u < 8; ++u) t[u] *= v;
    store8(rel_const + (size_t)slot * 64 + f0, t);
  }
}

// ================= K2..K4: propagation step (HEAD fuses predictor) =============
template <int HEAD>
__global__ __launch_bounds__(TPB, 4) void k_prop(
    const float* __restrict__ rp_w, const float* __restrict__ pp_w,
    const int* __restrict__ eidx, const float* __restrict__ evalid,
    const float* __restrict__ p_const, const float* __restrict__ rel_const,
    const float* __restrict__ effIn, float* __restrict__ effOut,
    const float* __restrict__ states,
    const float* __restrict__ pr_w1, const float* __restrict__ pr_b1,
    const float* __restrict__ pr_w2, const float* __restrict__ pr_b2,
    float* __restrict__ out) {
  __shared__ float act[64 * 65];
  __shared__ float agg[64 * 9];
  const int tid = threadIdx.x;
  const int wav = tid >> 6, lane = tid & 63;
  const int blk = blockIdx.x;
  const int node0 = blk * NPB;
  const int f0 = __builtin_amdgcn_readfirstlane(wav * 8);
  const int col = lane;
  const int slot = blk * 64 + col;
  const int nd = node0 + (col >> 3);
  const int nb = nd & ~(N - 1);
  const int j = nb + eidx[slot];
  float r[8];
  load8(r, effIn + (size_t)nd * 64 + f0);           // eff_r
  stage8(act, col, f0, r);
  __syncthreads();
  float t[8];
  load8(t, rel_const + (size_t)slot * 64 + f0);
  mv8(t, rp_w + 4096 + f0, act, col);               // rows 64..127 (eff_r)
  __syncthreads();
  load8(r, effIn + (size_t)j * 64 + f0);            // eff_s (gather)
  stage8(act, col, f0, r);
  __syncthreads();
  mv8(t, rp_w + 8192 + f0, act, col);               // rows 128..191 (eff_s)
  const float v = evalid[slot];
  #pragma unroll
  for (int u = 0; u < 8; ++u) {
    float x = fmaxf(t[u], 0.f) * v;                 // relu(rel_eff) * valid
    x += __shfl_xor(x, 1);                          // sum node's 8 slots
    x += __shfl_xor(x, 2);
    x += __shfl_xor(x, 4);
    t[u] = x;
  }
  {  // lane (col) writes one feature: e-th of its strip (static-select, no scratch)
    const int e = col & 7, n = col >> 3;
    float val = t[0];
    #pragma unroll
    for (int u = 1; u < 8; ++u) val = (e == u) ? t[u] : val;
    agg[(f0 + e) * 9 + n] = val;
  }
  __syncthreads();
  // pp1 matvec: wave = node, lane = feature
  const int onode = node0 + wav;
  float o = p_const[(size_t)onode * 64 + lane];
  #pragma unroll 4
  for (int g = 0; g < 64; ++g)
    o = fmaf(agg[g * 9 + wav], pp_w[4096 + g * 64 + lane], o);
  const float er = effIn[(size_t)onode * 64 + lane];
  const float ov = fmaxf(o + er, 0.f);
  if (HEAD == 0) {
    effOut[(size_t)onode * 64 + lane] = ov;
  } else {
    __syncthreads();                                // agg reads done
    agg[lane * 9 + wav] = ov;                       // stage final eff [k][n]
    __syncthreads();
    float h = pr_b1[lane];
    #pragma unroll 4
    for (int k = 0; k < 64; ++k)
      h = fmaf(agg[k * 9 + wav], pr_w1[k * 64 + lane], h);
    h = fmaxf(h, 0.f);
    float p0 = h * pr_w2[lane * 3];
    float p1 = h * pr_w2[lane * 3 + 1];
    float p2 = h * pr_w2[lane * 3 + 2];
    #pragma unroll
    for (int m = 1; m < 64; m <<= 1) {
      p0 += __shfl_xor(p0, m);
      p1 += __shfl_xor(p1, m);
      p2 += __shfl_xor(p2, m);
    }
    if (lane == 0) {
      out[onode * 3]     = states[onode * 3]     + p0 + pr_b2[0];
      out[onode * 3 + 1] = states[onode * 3 + 1] + p1 + pr_b2[1];
      out[onode * 3 + 2] = states[onode * 3 + 2] + p2 + pr_b2[2];
    }
  }
}

extern "C" void kernel_launch(void* const* d_in, const int* in_sizes, int n_in,
                              void* d_out, int out_size, void* d_ws, size_t ws_size,
                              hipStream_t stream) {
  const float* states  = (const float*)d_in[0];
  const float* a_cur   = (const float*)d_in[1];
  const float* s_delta = (const float*)d_in[2];
  const void*  maskp   = d_in[3];
  const void*  toolp   = d_in[4];
  const float* pe_w1 = (const float*)d_in[6];
  const float* pe_b1 = (const float*)d_in[7];
  const float* pe_w2 = (const float*)d_in[8];
  const float* pe_b2 = (const float*)d_in[9];
  const float* re_w1 = (const float*)d_in[10];
  const float* re_b1 = (const float*)d_in[11];
  const float* re_w2 = (const float*)d_in[12];
  const float* re_b2 = (const float*)d_in[13];
  const float* re_w3 = (const float*)d_in[14];
  const float* re_b3 = (const float*)d_in[15];
  const float* rp_w  = (const float*)d_in[16];
  const float* rp_b  = (const float*)d_in[17];
  const float* pp_w  = (const float*)d_in[18];
  const float* pp_b  = (const float*)d_in[19];
  const float* pr_w1 = (const float*)d_in[20];
  const float* pr_b1 = (const float*)d_in[21];
  const float* pr_w2 = (const float*)d_in[22];
  const float* pr_b2 = (const float*)d_in[23];

  char* w = (char*)d_ws;
  int*   eidx      = (int*)w;   w += (size_t)NSLOTS * 4;
  float* evalid    = (float*)w; w += (size_t)NSLOTS * 4;
  float* p_const   = (float*)w; w += (size_t)NODES * 64 * 4;
  float* rel_const = (float*)w; w += (size_t)NSLOTS * 64 * 4;
  float* effA      = (float*)w; w += (size_t)NODES * 64 * 4;
  float* effB      = (float*)w; w += (size_t)NODES * 64 * 4;
  float* out       = (float*)d_out;

  k_front<<<NBLK, TPB, 0, stream>>>(states, maskp, toolp, a_cur, s_delta,
      pe_w1, pe_b1, pe_w2, pe_b2, re_w1, re_b1, re_w2, re_b2, re_w3, re_b3,
      rp_w, rp_b, pp_w, pp_b, eidx, evalid, p_const, rel_const, effA);
  k_prop<0><<<NBLK, TPB, 0, stream>>>(rp_w, pp_w, eidx, evalid, p_const,
      rel_const, effA, effB, states, pr_w1, pr_b1, pr_w2, pr_b2, out);
  k_prop<0><<<NBLK, TPB, 0, stream>>>(rp_w, pp_w, eidx, evalid, p_const,
      rel_const, effB, effA, states, pr_w1, pr_b1, pr_w2, pr_b2, out);
  k_prop<1><<<NBLK, TPB, 0, stream>>>(rp_w, pp_w, eidx, evalid, p_const,
      rel_const, effA, effB, states, pr_w1, pr_b1, pr_w2, pr_b2, out);
}

// Round 9
// 161.795 us; speedup vs baseline: 5.8850x; 1.1856x over previous
//
#include <hip/hip_runtime.h>
#include <math.h>

#define DEV __device__ __forceinline__

constexpr int BB = 2, N = 2048, KK = 8;
constexpr int NODES = BB * N;          // 4096
constexpr int NSLOTS = NODES * KK;     // 32768
constexpr int NPB = 8;                 // nodes per block
constexpr int TPB = 512;               // 8 waves
constexpr int NBLK = NODES / NPB;      // 512 blocks

typedef __attribute__((ext_vector_type(8))) short short8v;
typedef __attribute__((ext_vector_type(4))) float float4v;
union S8 { short8v v; unsigned u[4]; unsigned short s[8]; };

// ---- bool input format detection ----
DEV int bool_mode(const void* p) {
  unsigned v = *(const unsigned*)p;
  if (v == 0x3f800000u) return 2;      // float32 1.0
  if (v <= 1u) return 1;               // int32 0/1
  return 0;                            // uint8
}
DEV bool read_mask(const void* p, int i, int mode) {
  if (mode == 2) return ((const float*)p)[i] != 0.f;
  if (mode == 1) return ((const int*)p)[i] != 0;
  return ((const unsigned char*)p)[i] != 0;
}

// ---- bf16 helpers (RNE) ----
DEV unsigned short f2bf(float x) {
  unsigned u = __builtin_bit_cast(unsigned, x);
  return (unsigned short)((u + 0x7FFFu + ((u >> 16) & 1u)) >> 16);
}
DEV unsigned pk2(float a, float b) {
  return (unsigned)f2bf(a) | ((unsigned)f2bf(b) << 16);
}

// ---- swizzled bf16 tile primitives: tile[row][kk], element-swizzle kk^=(row&7)<<3
DEV short8v rdA(const unsigned short* T, int row, int kk0) {
  return *(const short8v*)&T[row * 64 + (kk0 ^ ((row & 7) << 3))];
}
// stage W (global [64 k][64 f], k-major) transposed into wT[f][k] bf16, swizzled
DEV void stage_wT(const float* __restrict__ W, unsigned short* wt, int t) {
  const int f = t & 63, k0 = (t >> 6) * 8;
  S8 p;
  #pragma unroll
  for (int q = 0; q < 4; ++q)
    p.u[q] = pk2(W[(k0 + 2 * q) * 64 + f], W[(k0 + 2 * q + 1) * 64 + f]);
  *(short8v*)&wt[f * 64 + (k0 ^ ((f & 7) << 3))] = p.v;
}
// stage one row (64 f32 from g) into tile row `row` (chunk kq of 8)
DEV void stage_row8(unsigned short* T, int row, int kq, const float* __restrict__ g) {
  const int k0 = kq * 8;
  float4 v0 = ((const float4*)(g + k0))[0];
  float4 v1 = ((const float4*)(g + k0))[1];
  S8 p;
  p.u[0] = pk2(v0.x, v0.y); p.u[1] = pk2(v0.z, v0.w);
  p.u[2] = pk2(v1.x, v1.y); p.u[3] = pk2(v1.z, v1.w);
  *(short8v*)&T[row * 64 + (k0 ^ ((row & 7) << 3))] = p.v;
}

#define LESS(da, ja, db, jb) ((da) < (db) || ((da) == (db) && (ja) < (jb)))
#define CE(a, b)                                                              \
  {                                                                           \
    bool sw_ = LESS(nd[b], nj[b], nd[a], nj[a]);                              \
    float t_ = nd[a]; int u_ = nj[a];                                         \
    if (sw_) { nd[a] = nd[b]; nj[a] = nj[b]; nd[b] = t_; nj[b] = u_; }        \
  }

struct SEdge { float px[N], py[N], pz[N], padd[N]; };                  // 32 KB
struct SMlpF { unsigned short A0[4096]; unsigned short A1[4096]; float hb[64 * 9]; };
union SUF { SEdge e; SMlpF m; };

// ================= K1: edges + node encoder + MFMA edge encoder ================
__global__ __launch_bounds__(TPB, 4) void k_front(
    const float* __restrict__ states, const void* maskp, const void* toolp,
    const float* __restrict__ a_cur, const float* __restrict__ s_delta,
    const float* __restrict__ pe_w1, const float* __restrict__ pe_b1,
    const float* __restrict__ pe_w2, const float* __restrict__ pe_b2,
    const float* __restrict__ re_w1, const float* __restrict__ re_b1,
    const float* __restrict__ re_w2, const float* __restrict__ re_b2,
    const float* __restrict__ re_w3, const float* __restrict__ re_b3,
    const float* __restrict__ rp_w, const float* __restrict__ rp_b,
    const float* __restrict__ pp_w, const float* __restrict__ pp_b,
    int* __restrict__ eidx, float* __restrict__ evalid,
    float* __restrict__ p_const, float* __restrict__ rel_const,
    float* __restrict__ eff0) {
  __shared__ SUF su;
  __shared__ unsigned short wt3[3][4096];
  __shared__ int   sl_idx[64];
  __shared__ float sl_val[64];
  const int tid = threadIdx.x;
  const int wav = tid >> 6, lane = tid & 63;
  const int blk = blockIdx.x;
  const int node0 = blk * NPB;
  const int slot0 = blk * 64;
  const int b = node0 >> 11;
  const int mm = bool_mode(maskp), mt = bool_mode(toolp);

  // ---------- phase 0: stage transposed bf16 weights (consumed after barriers)
  stage_wT(re_w2, wt3[0], tid);
  stage_wT(re_w3, wt3[1], tid);
  stage_wT(rp_w,  wt3[2], tid);

  // ---------- phase 1: 8-NN edges, one node per wave (proven R2/R5 scan) ------
  {
    for (int j = tid; j < N; j += TPB) {
      const float* s = states + (size_t)(b * N + j) * 3;
      su.e.px[j] = s[0]; su.e.py[j] = s[1]; su.e.pz[j] = s[2];
      su.e.padd[j] = read_mask(maskp, b * N + j, mm) ? 0.f : 1e10f;
    }
    __syncthreads();
    const int node = node0 + wav;
    const int i = node & (N - 1);
    const bool mi = read_mask(maskp, node, mm);
    const bool ti = read_mask(toolp, node, mt);   // tool receivers: no edges
    float td[KK]; int tj[KK];
    #pragma unroll
    for (int k = 0; k < KK; ++k) { td[k] = 3.0e38f; tj[k] = 0; }
    if (mi && !ti) {
      const float sx = su.e.px[i], sy = su.e.py[i], sz = su.e.pz[i];
      #pragma unroll 4
      for (int it = 0; it < N / 64; ++it) {
        int j = lane + it * 64;
        float dx = sx - su.e.px[j], dy = sy - su.e.py[j], dz = sz - su.e.pz[j];
        float dis = __fadd_rn(__fadd_rn(__fmul_rn(dx, dx), __fmul_rn(dy, dy)),
                              __fmul_rn(dz, dz));
        float dd = __fadd_rn(dis, su.e.padd[j]);    // masked -> exactly 1e10
        if (dd < td[KK - 1]) {                      // strict < == stable
          float cd = dd; int cj = j;
          #pragma unroll
          for (int m = 0; m < KK; ++m) {
            bool sw = cd < td[m];
            float od = td[m]; int oj = tj[m];
            td[m] = sw ? cd : od; tj[m] = sw ? cj : oj;
            cd = sw ? od : cd;   cj = sw ? oj : cj;
          }
        }
      }
      #pragma unroll
      for (int m = 1; m < 64; m <<= 1) {
        float pd[KK]; int pj[KK];
        #pragma unroll
        for (int r = 0; r < KK; ++r) {
          pd[r] = __shfl_xor(td[r], m);
          pj[r] = __shfl_xor(tj[r], m);
        }
        float nd[KK]; int nj[KK];
        #pragma unroll
        for (int r = 0; r < KK; ++r) {
          float ad = td[r]; int aj = tj[r];
          float bd = pd[KK - 1 - r]; int bj = pj[KK - 1 - r];
          bool tb = LESS(bd, bj, ad, aj);
          nd[r] = tb ? bd : ad; nj[r] = tb ? bj : aj;
        }
        CE(0, 4) CE(1, 5) CE(2, 6) CE(3, 7)
        CE(0, 2) CE(1, 3) CE(4, 6) CE(5, 7)
        CE(0, 1) CE(2, 3) CE(4, 5) CE(6, 7)
        #pragma unroll
        for (int r = 0; r < KK; ++r) { td[r] = nd[r]; tj[r] = nj[r]; }
      }
    }
    if (lane == 0) {
      const float T2 = (float)(0.12 * 0.12);
      const bool ok = mi && !ti;
      #pragma unroll
      for (int k = 0; k < KK; ++k) {
        float v = (ok && td[k] < T2) ? 1.f : 0.f;
        sl_idx[wav * KK + k] = tj[k];
        sl_val[wav * KK + k] = v;
        eidx[(node0 + wav) * KK + k] = tj[k];
        evalid[(node0 + wav) * KK + k] = v;
      }
    }
    __syncthreads();
  }

  // ---------- phase 2: node encoder, exact f32 (wave = node, lane = feature) --
  {
    float* hb = su.m.hb;
    const int nd = node0 + wav;
    const int i = nd & (N - 1);
    const int f = lane;
    float sd[9];
    #pragma unroll
    for (int k = 0; k < 9; ++k) sd[k] = s_delta[(b * 9 + k) * N + i];
    const float a = a_cur[nd];
    float x = pe_b1[f];
    #pragma unroll
    for (int k = 0; k < 9; ++k) x = fmaf(sd[k], pe_w1[k * 64 + f], x);
    x = fmaf(a, pe_w1[576 + f] + pe_w1[640 + f] + pe_w1[704 + f], x);
    x = fmaxf(x, 0.f);
    hb[f * 9 + wav] = x;
    __syncthreads();
    float y = pe_b2[f];
    #pragma unroll 4
    for (int k = 0; k < 64; ++k) y = fmaf(hb[k * 9 + wav], pe_w2[k * 64 + f], y);
    y = fmaxf(y, 0.f);
    eff0[(size_t)nd * 64 + f] = y;        // p_enc == initial effect
    __syncthreads();
    hb[f * 9 + wav] = y;
    __syncthreads();
    float z = pp_b[f];
    #pragma unroll 4
    for (int k = 0; k < 64; ++k) z = fmaf(hb[k * 9 + wav], pp_w[k * 64 + f], z);
    p_const[(size_t)nd * 64 + f] = z;
    __syncthreads();
  }

  // ---------- phase 3: edge encoder. L1 = VALU f32 -> bf16 A0; L2..L4 = MFMA --
  {
    unsigned short* A0 = su.m.A0;
    unsigned short* A1 = su.m.A1;
    const int f0 = __builtin_amdgcn_readfirstlane(wav * 8);
    const int col = lane;
    const int nd = node0 + (col >> 3);
    const int nb = nd & ~(N - 1);
    const int j = nb + sl_idx[col];
    const float a_r = a_cur[nd], a_s = a_cur[j];
    const float dx = states[nd * 3]     - states[j * 3];
    const float dy = states[nd * 3 + 1] - states[j * 3 + 1];
    const float dz = states[nd * 3 + 2] - states[j * 3 + 2];
    float t[8];
    #pragma unroll
    for (int u = 0; u < 8; ++u) {
      const int f = f0 + u;
      float x = re_b1[f];
      x = fmaf(a_r, re_w1[f], x);
      x = fmaf(a_s, re_w1[64 + f], x);
      x = fmaf(dx, re_w1[128 + f], x);
      x = fmaf(dy, re_w1[192 + f], x);
      x = fmaf(dz, re_w1[256 + f], x);
      t[u] = fmaxf(x, 0.f);
    }
    #pragma unroll
    for (int u = 0; u < 8; u += 2) {
      int idx = col * 64 + ((f0 + u) ^ ((col & 7) << 3));
      *(unsigned*)&A0[idx] = pk2(t[u], t[u + 1]);
    }
    __syncthreads();

    const int m = wav & 3, h = wav >> 2;
    const int n0t = 2 * h, n1t = n0t + 1;
    const int rowA = m * 16 + (lane & 15);
    const int fc0 = n0t * 16 + (lane & 15), fc1 = n1t * 16 + (lane & 15);
    const unsigned long long vm = __ballot(sl_val[lane] != 0.f);

    // L2: A0 x re_w2 (+re_b2, relu) -> A1
    {
      float b0 = re_b2[fc0], b1 = re_b2[fc1];
      float4v c0 = {b0, b0, b0, b0}, c1 = {b1, b1, b1, b1};
      #pragma unroll
      for (int ks = 0; ks < 2; ++ks) {
        const int kk0 = ks * 32 + (lane >> 4) * 8;
        short8v a  = rdA(A0, rowA, kk0);
        short8v w0 = rdA(wt3[0], fc0, kk0);
        short8v w1 = rdA(wt3[0], fc1, kk0);
        c0 = __builtin_amdgcn_mfma_f32_16x16x32_bf16(a, w0, c0, 0, 0, 0);
        c1 = __builtin_amdgcn_mfma_f32_16x16x32_bf16(a, w1, c1, 0, 0, 0);
      }
      #pragma unroll
      for (int r = 0; r < 4; ++r) {
        int slot = m * 16 + (lane >> 4) * 4 + r;
        A1[slot * 64 + (fc0 ^ ((slot & 7) << 3))] = f2bf(fmaxf(c0[r], 0.f));
        A1[slot * 64 + (fc1 ^ ((slot & 7) << 3))] = f2bf(fmaxf(c1[r], 0.f));
      }
    }
    __syncthreads();
    // L3: A1 x re_w3 (+re_b3, relu) -> A0
    {
      float b0 = re_b3[fc0], b1 = re_b3[fc1];
      float4v c0 = {b0, b0, b0, b0}, c1 = {b1, b1, b1, b1};
      #pragma unroll
      for (int ks = 0; ks < 2; ++ks) {
        const int kk0 = ks * 32 + (lane >> 4) * 8;
        short8v a  = rdA(A1, rowA, kk0);
        short8v w0 = rdA(wt3[1], fc0, kk0);
        short8v w1 = rdA(wt3[1], fc1, kk0);
        c0 = __builtin_amdgcn_mfma_f32_16x16x32_bf16(a, w0, c0, 0, 0, 0);
        c1 = __builtin_amdgcn_mfma_f32_16x16x32_bf16(a, w1, c1, 0, 0, 0);
      }
      #pragma unroll
      for (int r = 0; r < 4; ++r) {
        int slot = m * 16 + (lane >> 4) * 4 + r;
        A0[slot * 64 + (fc0 ^ ((slot & 7) << 3))] = f2bf(fmaxf(c0[r], 0.f));
        A0[slot * 64 + (fc1 ^ ((slot & 7) << 3))] = f2bf(fmaxf(c1[r], 0.f));
      }
    }
    __syncthreads();
    // L4: A0 x rp_w[0:64] (+rp_b, NO relu), x valid -> global rel_const (f32)
    {
      float b0 = rp_b[fc0], b1 = rp_b[fc1];
      float4v c0 = {b0, b0, b0, b0}, c1 = {b1, b1, b1, b1};
      #pragma unroll
      for (int ks = 0; ks < 2; ++ks) {
        const int kk0 = ks * 32 + (lane >> 4) * 8;
        short8v a  = rdA(A0, rowA, kk0);
        short8v w0 = rdA(wt3[2], fc0, kk0);
        short8v w1 = rdA(wt3[2], fc1, kk0);
        c0 = __builtin_amdgcn_mfma_f32_16x16x32_bf16(a, w0, c0, 0, 0, 0);
        c1 = __builtin_amdgcn_mfma_f32_16x16x32_bf16(a, w1, c1, 0, 0, 0);
      }
      #pragma unroll
      for (int r = 0; r < 4; ++r) {
        int slot = m * 16 + (lane >> 4) * 4 + r;
        float v = (float)((vm >> slot) & 1ull);
        rel_const[(size_t)(slot0 + slot) * 64 + fc0] = c0[r] * v;
        rel_const[(size_t)(slot0 + slot) * 64 + fc1] = c1[r] * v;
      }
    }
  }
}

// ================= K2..K4: propagation step (HEAD fuses predictor) =============
template <int HEAD>
__global__ __launch_bounds__(TPB, 4) void k_prop(
    const float* __restrict__ rp_w, const float* __restrict__ pp_w,
    const int* __restrict__ eidx, const float* __restrict__ evalid,
    const float* __restrict__ p_const, const float* __restrict__ rel_const,
    const float* __restrict__ effIn, float* __restrict__ effOut,
    const float* __restrict__ states,
    const float* __restrict__ pr_w1, const float* __restrict__ pr_b1,
    const float* __restrict__ pr_w2, const float* __restrict__ pr_b2,
    float* __restrict__ out) {
  __shared__ unsigned short AS[4096];      // sender eff bf16 [64 slots][64]
  __shared__ unsigned short EN[512];       // block-node eff bf16 [8][64]
  __shared__ unsigned short wt2[2][4096];  // rp_w rows 64..127 / 128..191, ^T
  __shared__ float agg[8 * 64];
  const int tid = threadIdx.x;
  const int wav = tid >> 6, lane = tid & 63;
  const int blk = blockIdx.x;
  const int node0 = blk * NPB;
  const int slot0 = blk * 64;
  const int nb = node0 & ~(N - 1);

  stage_wT(rp_w + 4096, wt2[0], tid);
  stage_wT(rp_w + 8192, wt2[1], tid);
  {  // stage sender eff (gather) as bf16
    const int slot = tid >> 3, kq = tid & 7;
    const int j = nb + eidx[slot0 + slot];
    stage_row8(AS, slot, kq, effIn + (size_t)j * 64);
  }
  if (tid < 64) {  // stage this block's 8 receiver effs
    const int n = tid >> 3, kq = tid & 7;
    stage_row8(EN, n, kq, effIn + (size_t)(node0 + n) * 64);
  }
  const unsigned long long vm = __ballot(evalid[slot0 + lane] != 0.f);
  __syncthreads();

  // GEMMs: rel2 = rel_const + effR x W1 + effS x W2 ; relu ; x valid ; agg
  {
    const int m = wav & 3, h = wav >> 2;
    const int n0t = 2 * h, n1t = n0t + 1;
    const int rowA = m * 16 + (lane & 15);
    const int nodeR = rowA >> 3;          // receiver node (block-local)
    const int fc0 = n0t * 16 + (lane & 15), fc1 = n1t * 16 + (lane & 15);
    float4v c0, c1;
    #pragma unroll
    for (int r = 0; r < 4; ++r) {
      int slot = m * 16 + (lane >> 4) * 4 + r;
      c0[r] = rel_const[(size_t)(slot0 + slot) * 64 + fc0];
      c1[r] = rel_const[(size_t)(slot0 + slot) * 64 + fc1];
    }
    #pragma unroll
    for (int ks = 0; ks < 2; ++ks) {
      const int kk0 = ks * 32 + (lane >> 4) * 8;
      short8v aR = rdA(EN, nodeR, kk0);
      short8v aS = rdA(AS, rowA, kk0);
      short8v w10 = rdA(wt2[0], fc0, kk0);
      short8v w11 = rdA(wt2[0], fc1, kk0);
      short8v w20 = rdA(wt2[1], fc0, kk0);
      short8v w21 = rdA(wt2[1], fc1, kk0);
      c0 = __builtin_amdgcn_mfma_f32_16x16x32_bf16(aR, w10, c0, 0, 0, 0);
      c1 = __builtin_amdgcn_mfma_f32_16x16x32_bf16(aR, w11, c1, 0, 0, 0);
      c0 = __builtin_amdgcn_mfma_f32_16x16x32_bf16(aS, w20, c0, 0, 0, 0);
      c1 = __builtin_amdgcn_mfma_f32_16x16x32_bf16(aS, w21, c1, 0, 0, 0);
    }
    float s0 = 0.f, s1 = 0.f;
    #pragma unroll
    for (int r = 0; r < 4; ++r) {
      int slot = m * 16 + (lane >> 4) * 4 + r;
      float v = (float)((vm >> slot) & 1ull);
      s0 += fmaxf(c0[r], 0.f) * v;
      s1 += fmaxf(c1[r], 0.f) * v;
    }
    s0 += __shfl_xor(s0, 16);             // combine the node's two reg-groups
    s1 += __shfl_xor(s1, 16);
    if (((lane >> 4) & 1) == 0) {
      const int an = m * 2 + (lane >> 5);
      agg[an * 64 + fc0] = s0;
      agg[an * 64 + fc1] = s1;
    }
  }
  __syncthreads();

  // pp1 + residual + relu (exact f32): wave = node, lane = feature
  const int onode = node0 + wav;
  float o = p_const[(size_t)onode * 64 + lane];
  #pragma unroll 4
  for (int g = 0; g < 64; ++g)
    o = fmaf(agg[wav * 64 + g], pp_w[4096 + g * 64 + lane], o);
  const float er = effIn[(size_t)onode * 64 + lane];
  const float ov = fmaxf(o + er, 0.f);
  if (HEAD == 0) {
    effOut[(size_t)onode * 64 + lane] = ov;
  } else {
    __syncthreads();                      // agg reads done
    agg[wav * 64 + lane] = ov;
    __syncthreads();
    float hh = pr_b1[lane];
    #pragma unroll 4
    for (int k = 0; k < 64; ++k)
      hh = fmaf(agg[wav * 64 + k], pr_w1[k * 64 + lane], hh);
    hh = fmaxf(hh, 0.f);
    float p0 = hh * pr_w2[lane * 3];
    float p1 = hh * pr_w2[lane * 3 + 1];
    float p2 = hh * pr_w2[lane * 3 + 2];
    #pragma unroll
    for (int m = 1; m < 64; m <<= 1) {
      p0 += __shfl_xor(p0, m);
      p1 += __shfl_xor(p1, m);
      p2 += __shfl_xor(p2, m);
    }
    if (lane == 0) {
      out[onode * 3]     = states[onode * 3]     + p0 + pr_b2[0];
      out[onode * 3 + 1] = states[onode * 3 + 1] + p1 + pr_b2[1];
      out[onode * 3 + 2] = states[onode * 3 + 2] + p2 + pr_b2[2];
    }
  }
}

extern "C" void kernel_launch(void* const* d_in, const int* in_sizes, int n_in,
                              void* d_out, int out_size, void* d_ws, size_t ws_size,
                              hipStream_t stream) {
  const float* states  = (const float*)d_in[0];
  const float* a_cur   = (const float*)d_in[1];
  const float* s_delta = (const float*)d_in[2];
  const void*  maskp   = d_in[3];
  const void*  toolp   = d_in[4];
  const float* pe_w1 = (const float*)d_in[6];
  const float* pe_b1 = (const float*)d_in[7];
  const float* pe_w2 = (const float*)d_in[8];
  const float* pe_b2 = (const float*)d_in[9];
  const float* re_w1 = (const float*)d_in[10];
  const float* re_b1 = (const float*)d_in[11];
  const float* re_w2 = (const float*)d_in[12];
  const float* re_b2 = (const float*)d_in[13];
  const float* re_w3 = (const float*)d_in[14];
  const float* re_b3 = (const float*)d_in[15];
  const float* rp_w  = (const float*)d_in[16];
  const float* rp_b  = (const float*)d_in[17];
  const float* pp_w  = (const float*)d_in[18];
  const float* pp_b  = (const float*)d_in[19];
  const float* pr_w1 = (const float*)d_in[20];
  const float* pr_b1 = (const float*)d_in[21];
  const float* pr_w2 = (const float*)d_in[22];
  const float* pr_b2 = (const float*)d_in[23];

  char* w = (char*)d_ws;
  int*   eidx      = (int*)w;   w += (size_t)NSLOTS * 4;
  float* evalid    = (float*)w; w += (size_t)NSLOTS * 4;
  float* p_const   = (float*)w; w += (size_t)NODES * 64 * 4;
  float* rel_const = (float*)w; w += (size_t)NSLOTS * 64 * 4;
  float* effA      = (float*)w; w += (size_t)NODES * 64 * 4;
  float* effB      = (float*)w; w += (size_t)NODES * 64 * 4;
  float* out       = (float*)d_out;

  k_front<<<NBLK, TPB, 0, stream>>>(states, maskp, toolp, a_cur, s_delta,
      pe_w1, pe_b1, pe_w2, pe_b2, re_w1, re_b1, re_w2, re_b2, re_w3, re_b3,
      rp_w, rp_b, pp_w, pp_b, eidx, evalid, p_const, rel_const, effA);
  k_prop<0><<<NBLK, TPB, 0, stream>>>(rp_w, pp_w, eidx, evalid, p_const,
      rel_const, effA, effB, states, pr_w1, pr_b1, pr_w2, pr_b2, out);
  k_prop<0><<<NBLK, TPB, 0, stream>>>(rp_w, pp_w, eidx, evalid, p_const,
      rel_const, effB, effA, states, pr_w1, pr_b1, pr_w2, pr_b2, out);
  k_prop<1><<<NBLK, TPB, 0, stream>>>(rp_w, pp_w, eidx, evalid, p_const,
      rel_const, effA, effB, states, pr_w1, pr_b1, pr_w2, pr_b2, out);
}